// Round 7
// baseline (610.535 us; speedup 1.0000x reference)
//
#include <hip/hip_runtime.h>
#include <stdint.h>

#define EPSF 1e-7f
#define MAXTAN 10.0f

typedef __bf16 bf16x8 __attribute__((ext_vector_type(8)));
typedef float floatx4 __attribute__((ext_vector_type(4)));
typedef __attribute__((address_space(3))) void lds_void_t;
typedef __attribute__((address_space(1))) void gbl_void_t;

__device__ __forceinline__ unsigned short f2bf(float x) {
  union { float f; uint32_t u; } v; v.f = x;
  uint32_t u = v.u;
  u += 0x7fffu + ((u >> 16) & 1u);   // RNE
  return (unsigned short)(u >> 16);
}
__device__ __forceinline__ float bf2f(unsigned short h) {
  union { uint32_t u; float f; } v; v.u = ((uint32_t)h) << 16;
  return v.f;
}

__device__ __forceinline__ int sniff_mode(const unsigned short* x) {
  int sane = 0;
  for (int i = 0; i < 128; ++i) {
    unsigned short h = x[i];
    int e = (h >> 7) & 0xFF;
    if ((h & 0x7FFF) == 0 || (e >= 96 && e <= 140)) ++sane;
  }
  return (sane >= 120) ? 1 : 0;
}

// ---------------- init: sniff dtype + convert biases ----------------
__global__ void k_init(const unsigned short* __restrict__ x, int* __restrict__ modeg,
                       const void* __restrict__ b1, const void* __restrict__ b2,
                       const void* __restrict__ b3, float* __restrict__ o1,
                       float* __restrict__ o2, float* __restrict__ o3) {
  __shared__ int mds;
  if (threadIdx.x == 0) {
    int m = sniff_mode(x);
    mds = m;
    if (blockIdx.x == 0) *modeg = m;
  }
  __syncthreads();
  int m = mds;
  int i = blockIdx.x * 256 + threadIdx.x;
  if (i < 4096) o1[i] = m ? bf2f(((const unsigned short*)b1)[i]) : ((const float*)b1)[i];
  if (i < 4096) o2[i] = m ? bf2f(((const unsigned short*)b2)[i]) : ((const float*)b2)[i];
  if (i < 1024) o3[i] = m ? bf2f(((const unsigned short*)b3)[i]) : ((const float*)b3)[i];
}

// ---------------- x prep: convert to bf16, compute logmap scale + x0 ----------------
__global__ void k_prep(const void* __restrict__ xv, unsigned short* __restrict__ xb,
                       float* __restrict__ sc0, float* __restrict__ x0c,
                       const int* __restrict__ mode) {
  const int row = blockIdx.x;
  const int tid = threadIdx.x;
  float4 v;
  if (*mode) {
    ushort4 u = ((const ushort4*)((const unsigned short*)xv + (size_t)row * 1024))[tid];
    v.x = bf2f(u.x); v.y = bf2f(u.y); v.z = bf2f(u.z); v.w = bf2f(u.w);
  } else {
    v = ((const float4*)((const float*)xv + (size_t)row * 1024))[tid];
  }
  ushort4 o;
  o.x = f2bf(v.x); o.y = f2bf(v.y); o.z = f2bf(v.z); o.w = f2bf(v.w);
  ((ushort4*)(xb + (size_t)row * 1024))[tid] = o;

  float s = v.x * v.x + v.y * v.y + v.z * v.z + v.w * v.w;
  if (tid == 0) s -= v.x * v.x;          // exclude time coordinate
  for (int off = 32; off; off >>= 1) s += __shfl_down(s, off, 64);
  __shared__ float red[4];
  if ((tid & 63) == 0) red[tid >> 6] = s;
  __syncthreads();
  if (tid == 0) {
    s = red[0] + red[1] + red[2] + red[3];
    float ns = fmaxf(sqrtf(s), EPSF);
    float d = acoshf(fmaxf(v.x, 1.0f + EPSF));
    sc0[row] = d / ns;
    x0c[row] = bf2f(o.x);
  }
}

// ---------------- weight convert to bf16 + col0 extraction ----------------
template<int K8>
__global__ void k_cvtw(const void* __restrict__ in, unsigned short* __restrict__ out,
                       const int* __restrict__ mode, int n8, float* __restrict__ c0) {
  int i = blockIdx.x * 256 + threadIdx.x;
  if (i >= n8) return;
  if (*mode) {
    uint4 g = ((const uint4*)in)[i];
    ((uint4*)out)[i] = g;
    if (i % K8 == 0) c0[i / K8] = bf2f((unsigned short)(g.x & 0xFFFFu));
  } else {
    float4 a = ((const float4*)in)[2 * i];
    float4 b = ((const float4*)in)[2 * i + 1];
    ushort4 oa, ob;
    oa.x = f2bf(a.x); oa.y = f2bf(a.y); oa.z = f2bf(a.z); oa.w = f2bf(a.w);
    ob.x = f2bf(b.x); ob.y = f2bf(b.y); ob.z = f2bf(b.z); ob.w = f2bf(b.w);
    ((ushort4*)out)[2 * i] = oa;
    ((ushort4*)out)[2 * i + 1] = ob;
    if (i % K8 == 0) c0[i / K8] = bf2f(oa.x);
  }
}

// ---------------- partial-sumsq fold -> scale + col0 grab ----------------
template<int NBLK>
__global__ void k_sc(const float* __restrict__ part, const unsigned short* __restrict__ y,
                     int stride, float* __restrict__ sc, float* __restrict__ c0,
                     float* __restrict__ ssout, int nrows) {
  int i = blockIdx.x * 256 + threadIdx.x;
  if (i >= nrows) return;
  float s = 0.f;
#pragma unroll
  for (int j = 0; j < NBLK; ++j) s += part[(size_t)i * NBLK + j];
  float n = fmaxf(sqrtf(fmaxf(s, 0.f)), EPSF);
  sc[i] = fminf(n, MAXTAN) / n;
  c0[i] = bf2f(y[(size_t)i * stride]);
  if (ssout) ssout[i] = s;
}

// ---------------- final: y3 bf16 + ss3 -> projx(safe_expmap0(y3)) ----------------
__global__ void k_final(const unsigned short* __restrict__ y, const float* __restrict__ ss,
                        void* __restrict__ outv, const int* __restrict__ mode) {
  const int row = blockIdx.x;
  const int tid = threadIdx.x;
  float n = fmaxf(sqrtf(fmaxf(ss[row], 0.f)), EPSF);
  float nc = fminf(n, MAXTAN);
  float a = sinhf(nc) / n;
  ushort4 u = ((const ushort4*)(y + (size_t)row * 1024))[tid];
  float4 o;
  o.x = bf2f(u.x) * a; o.y = bf2f(u.y) * a;
  o.z = bf2f(u.z) * a; o.w = bf2f(u.w) * a;
  if (tid == 0) o.x = coshf(nc);
  if (*mode) {
    ushort4 o16;
    o16.x = f2bf(o.x); o16.y = f2bf(o.y); o16.z = f2bf(o.z); o16.w = f2bf(o.w);
    ((ushort4*)outv)[(size_t)row * 256 + tid] = o16;
  } else {
    ((float4*)outv)[(size_t)row * 256 + tid] = o;
  }
}

// ---------------- legacy 128x128 NT GEMM (kept for GEMM3) ----------------
template<int N, int K, int NBLK, int GX>
__global__ __launch_bounds__(256, 4) void k_gemm_bt(
    const unsigned short* __restrict__ A,
    const unsigned short* __restrict__ B,
    const float* __restrict__ bias,
    const float* __restrict__ sc,
    const float* __restrict__ c0f,
    const float* __restrict__ wc0,
    unsigned short* __restrict__ Cb,
    float* __restrict__ part)
{
  __shared__ __align__(16) unsigned short As[128 * 32];
  __shared__ __align__(16) unsigned short Bs[128 * 32];

  const int tid  = threadIdx.x;
  const int wave = tid >> 6;
  const int lane = tid & 63;
  const int quad = lane >> 4;
  const int m16  = lane & 15;

  const int j = blockIdx.x & 7;
  const int k = blockIdx.x >> 3;
  int bxi, byi;
  if (GX == 32) {
    bxi = 16 * (j & 1) + (k & 15);
    byi = 16 * (j >> 1) + (k >> 4);
  } else {
    bxi = k & 7;
    byi = 8 * j + (k >> 3);
  }
  const int bm = byi * 128;
  const int bn = bxi * 128;

  const int srow = lane >> 2;
  const int scol = (((lane & 3) ^ ((srow >> 1) & 3)) << 3);

  const int wm = (wave >> 1) << 6;
  const int wn = (wave & 1) << 6;

  const int rsw = ((quad ^ ((m16 >> 1) & 3)) << 3);

  const int c0i = wave * 2;
  const unsigned short* ga0 = A + (size_t)(bm + c0i * 16 + srow) * K + scol;
  const unsigned short* ga1 = ga0 + (size_t)16 * K;
  const unsigned short* gb0 = B + (size_t)(bn + c0i * 16 + srow) * K + scol;
  const unsigned short* gb1 = gb0 + (size_t)16 * K;

  floatx4 acc[4][4];
#pragma unroll
  for (int i = 0; i < 4; ++i)
#pragma unroll
    for (int jj = 0; jj < 4; ++jj)
#pragma unroll
      for (int r = 0; r < 4; ++r) acc[i][jj][r] = 0.0f;

  for (int k0 = 0; k0 < K; k0 += 32) {
    __builtin_amdgcn_global_load_lds((gbl_void_t*)(void*)ga0,
                                     (lds_void_t*)(As + c0i * 512), 16, 0, 0);
    __builtin_amdgcn_global_load_lds((gbl_void_t*)(void*)ga1,
                                     (lds_void_t*)(As + c0i * 512 + 512), 16, 0, 0);
    __builtin_amdgcn_global_load_lds((gbl_void_t*)(void*)gb0,
                                     (lds_void_t*)(Bs + c0i * 512), 16, 0, 0);
    __builtin_amdgcn_global_load_lds((gbl_void_t*)(void*)gb1,
                                     (lds_void_t*)(Bs + c0i * 512 + 512), 16, 0, 0);
    ga0 += 32; ga1 += 32; gb0 += 32; gb1 += 32;
    __syncthreads();

    bf16x8 af[4], bfg[4];
#pragma unroll
    for (int t = 0; t < 4; ++t) {
      af[t]  = *(const bf16x8*)(As + (wm + t * 16 + m16) * 32 + rsw);
      bfg[t] = *(const bf16x8*)(Bs + (wn + t * 16 + m16) * 32 + rsw);
    }
#pragma unroll
    for (int mt = 0; mt < 4; ++mt)
#pragma unroll
      for (int nt = 0; nt < 4; ++nt)
        acc[mt][nt] = __builtin_amdgcn_mfma_f32_16x16x32_bf16(af[mt], bfg[nt], acc[mt][nt], 0, 0, 0);
    __syncthreads();
  }

#pragma unroll
  for (int mt = 0; mt < 4; ++mt) {
#pragma unroll
    for (int r = 0; r < 4; ++r) {
      const int gm = bm + wm + mt * 16 + quad * 4 + r;
      const float scv = sc[gm];
      const float c0v = c0f[gm];
      float sq = 0.f;
#pragma unroll
      for (int nt = 0; nt < 4; ++nt) {
        const int gn = bn + wn + nt * 16 + m16;
        float v = scv * (acc[mt][nt][r] - c0v * wc0[gn]) + bias[gn];
        Cb[(size_t)gm * N + gn] = f2bf(v);
        sq += (gn == 0) ? 0.f : v * v;
      }
      sq += __shfl_xor(sq, 1, 64);
      sq += __shfl_xor(sq, 2, 64);
      sq += __shfl_xor(sq, 4, 64);
      sq += __shfl_xor(sq, 8, 64);
      if (m16 == 0) part[(size_t)gm * NBLK + 2 * bxi + (wave & 1)] = sq;
    }
  }
}

// ---------------- 128x256 NT GEMM, 2-blocks/CU deep pipeline (R7) ----------------
// THE R3-R6 LESSON: 1 block/CU (128KB LDS) -> 2 same-block waves/SIMD in barrier
// lockstep; every intra-block schedule tweak capped MfmaUtil at ~47-53%. m97's 912TF
// came from CROSS-BLOCK wave overlap (m114). This kernel restores it:
//   tile 128Mx256N, 256 thr = 4 waves (1M x 4N), per-wave 128x64 out, acc[8][4];
//   3-slot LDS ring of (A 128x32 + B 256x32) = 24KB/slot = 72KB -> 2 blocks/CU
//   (144<=160KB); each SIMD gets 1 wave from EACH block -> no shared barrier ->
//   one block's MFMA stretch covers the other's stage/read window automatically.
// Per iter: {6 GLL stage(t+2) -> slot (t+2)%3; 12 ds_read frags tile t; 32 MFMA
//   (setprio); vmcnt(6); s_barrier}. Ledger: end of iter t, outstanding <=6 =
//   stage(t+2) -> tile t+1 resident for iter t+1 (block-wide via barrier).
// WAR: stage(t+2) writes slot (t-1)%3; its readers (iter t-1) consumed into regs
//   (MFMA lgkmcnt) before iter t-1's barrier, which precedes this GLL issue.
// Main loop unrolled x3 (compile-time slots); (NT-2)%3==0 for K=1024/4096; tail =
//   2 stage-free bodies with one vmcnt(0)+barrier between (drains stage(NT-1)).
// Granule swizzle identical to verified scheme: staging row=tid>>2, granule
//   (tid&3)^((tid>>3)&3); read granule quad^((m16>>1)&3) -- 0 conflicts measured.
// Epilogue: y = sc[m]*(acc - c0f[m]*wc0[n]) + bias[n]; partials
//   part[gm*(4*NBX) + bxi*4 + wc] (NBX=N/256; k_sc<64> for N=4096).
template<int N, int K>
__global__ __launch_bounds__(256, 2) void k_g128(
    const unsigned short* __restrict__ A,
    const unsigned short* __restrict__ B,
    const float* __restrict__ bias,
    const float* __restrict__ sc,
    const float* __restrict__ c0f,
    const float* __restrict__ wc0,
    unsigned short* __restrict__ Cb,
    float* __restrict__ part)
{
  constexpr int NT = K / 32;
  static_assert(NT >= 5 && (NT - 2) % 3 == 0, "NT must be 2 mod 3, >=5");
  constexpr int NBX = N / 256;
  static_assert(NBX == 16, "grid swizzle assumes N==4096");
  __shared__ __align__(16) unsigned short S[3][12288];   // slot = A[128][32] + B[256][32]

  const int tid  = threadIdx.x;
  const int wc   = tid >> 6;         // wave 0..3 = N-column index
  const int lane = tid & 63;
  const int quad = lane >> 4;
  const int m16  = lane & 15;

  // bijective XCD swizzle: 1024 blocks = 8 XCDs x 128; per-XCD patch = 8bxi x 16byi
  const int j  = blockIdx.x & 7;
  const int kk = blockIdx.x >> 3;                // 0..127
  const int bxi = 8 * (j & 1) + (kk & 7);        // 0..15  (N/256)
  const int byi = 16 * (j >> 1) + (kk >> 3);     // 0..63  (M/128)
  const int bm = byi * 128;
  const int bn = bxi * 256;

  // staging: thread -> row tid>>2 (0..63 per GLL region), granule tid&3 (pre-swizzled)
  const int gsw8 = (((tid & 3) ^ ((tid >> 3) & 3)) << 3);
  const int srow = tid >> 2;
  const unsigned short* pA0 = A + (size_t)(bm + srow) * K + gsw8;
  const unsigned short* pA1 = pA0 + (size_t)64 * K;
  const unsigned short* pB0 = B + (size_t)(bn + srow) * K + gsw8;
  const unsigned short* pB1 = pB0 + (size_t)64 * K;
  const unsigned short* pB2 = pB0 + (size_t)128 * K;
  const unsigned short* pB3 = pB0 + (size_t)192 * K;
  char* LDw = (char*)&S[0][0] + wc * 1024;       // wave's stripe within a 4KB region

  // read side: swizzled granule + byte bases (all ds offsets compile-time, <64KB)
  const int rsw8 = ((quad ^ ((m16 >> 1) & 3)) << 3);
  const char* Ab = (const char*)&S[0][0] + m16 * 64 + rsw8 * 2;                     // A region
  const char* Bb = (const char*)&S[0][0] + 8192 + (wc * 64 + m16) * 64 + rsw8 * 2;  // B region

  floatx4 acc[8][4];
#pragma unroll
  for (int i = 0; i < 8; ++i)
#pragma unroll
    for (int jj = 0; jj < 4; ++jj)
#pragma unroll
      for (int r = 0; r < 4; ++r) acc[i][jj][r] = 0.0f;

#define GLL(SRC, DST) __builtin_amdgcn_global_load_lds((gbl_void_t*)(void*)(SRC), (lds_void_t*)(DST), 16, 0, 0)
#define STG(SL, CO) { \
    GLL(pA0 + (CO), LDw + (SL) * 24576 +     0); \
    GLL(pA1 + (CO), LDw + (SL) * 24576 +  4096); \
    GLL(pB0 + (CO), LDw + (SL) * 24576 +  8192); \
    GLL(pB1 + (CO), LDw + (SL) * 24576 + 12288); \
    GLL(pB2 + (CO), LDw + (SL) * 24576 + 16384); \
    GLL(pB3 + (CO), LDw + (SL) * 24576 + 20480); }
#define ARD(SL, M_) (*(const bf16x8*)(Ab + (SL) * 24576 + (M_) * 1024))
#define BRD(SL, N_) (*(const bf16x8*)(Bb + (SL) * 24576 + (N_) * 1024))

  // prologue: stage tile0 -> slot0, tile1 -> slot1; vmcnt(6) -> tile0 resident
  STG(0, 0) STG(1, 32)
  pA0 += 64; pA1 += 64; pB0 += 64; pB1 += 64; pB2 += 64; pB3 += 64;   // -> tile2 col
  asm volatile("s_waitcnt vmcnt(6)" ::: "memory");
  __builtin_amdgcn_s_barrier();

  // BODY: compute slot SC (tile t), stage tile t+2 into slot SS from ptr+CO
#define BODY(SC, SS, CO)                                                               \
  {                                                                                    \
    STG(SS, CO)                                                                        \
    bf16x8 a_[8], b_[4];                                                               \
    _Pragma("unroll")                                                                  \
    for (int m = 0; m < 8; ++m) a_[m] = ARD(SC, m);                                    \
    _Pragma("unroll")                                                                  \
    for (int n = 0; n < 4; ++n) b_[n] = BRD(SC, n);                                    \
    __builtin_amdgcn_s_setprio(1);                                                     \
    _Pragma("unroll")                                                                  \
    for (int f = 0; f < 8; ++f)                                                        \
      _Pragma("unroll")                                                                \
      for (int n = 0; n < 4; ++n)                                                      \
        acc[f][n] = __builtin_amdgcn_mfma_f32_16x16x32_bf16(a_[f], b_[n], acc[f][n], 0, 0, 0); \
    __builtin_amdgcn_s_setprio(0);                                                     \
    asm volatile("s_waitcnt vmcnt(6)" ::: "memory");                                   \
    __builtin_amdgcn_s_barrier();                                                      \
  }
#define TBODY(SC)                                                                      \
  {                                                                                    \
    bf16x8 a_[8], b_[4];                                                               \
    _Pragma("unroll")                                                                  \
    for (int m = 0; m < 8; ++m) a_[m] = ARD(SC, m);                                    \
    _Pragma("unroll")                                                                  \
    for (int n = 0; n < 4; ++n) b_[n] = BRD(SC, n);                                    \
    __builtin_amdgcn_s_setprio(1);                                                     \
    _Pragma("unroll")                                                                  \
    for (int f = 0; f < 8; ++f)                                                        \
      _Pragma("unroll")                                                                \
      for (int n = 0; n < 4; ++n)                                                      \
        acc[f][n] = __builtin_amdgcn_mfma_f32_16x16x32_bf16(a_[f], b_[n], acc[f][n], 0, 0, 0); \
    __builtin_amdgcn_s_setprio(0);                                                     \
  }

  // main: t = 0 .. NT-3, groups of 3 (slots cycle 0,1,2; stage slots 2,0,1)
  for (int g = 0; g < (NT - 2) / 3; ++g) {
    BODY(0, 2, 0)
    BODY(1, 0, 32)
    BODY(2, 1, 64)
    pA0 += 96; pA1 += 96; pB0 += 96; pB1 += 96; pB2 += 96; pB3 += 96;
  }

  // tail: tile NT-2 (slot 0), drain stage(NT-1), tile NT-1 (slot 1)
  TBODY(0)
  asm volatile("s_waitcnt vmcnt(0)" ::: "memory");
  __builtin_amdgcn_s_barrier();
  TBODY(1)

#undef TBODY
#undef BODY
#undef ARD
#undef BRD
#undef STG
#undef GLL

  // epilogue: C/D layout col = lane&15, row = quad*4 + r
#pragma unroll
  for (int mt = 0; mt < 8; ++mt) {
#pragma unroll
    for (int r = 0; r < 4; ++r) {
      const int gm = bm + mt * 16 + quad * 4 + r;
      const float scv = sc[gm];
      const float c0v = c0f[gm];
      float sq = 0.f;
#pragma unroll
      for (int nt = 0; nt < 4; ++nt) {
        const int gn = bn + wc * 64 + nt * 16 + m16;
        float v = scv * (acc[mt][nt][r] - c0v * wc0[gn]) + bias[gn];
        Cb[(size_t)gm * N + gn] = f2bf(v);
        sq += (gn == 0) ? 0.f : v * v;
      }
      sq += __shfl_xor(sq, 1, 64);
      sq += __shfl_xor(sq, 2, 64);
      sq += __shfl_xor(sq, 4, 64);
      sq += __shfl_xor(sq, 8, 64);
      if (m16 == 0) part[(size_t)gm * (4 * NBX) + bxi * 4 + wc] = sq;
    }
  }
}

extern "C" void kernel_launch(void* const* d_in, const int* in_sizes, int n_in,
                              void* d_out, int out_size, void* d_ws, size_t ws_size,
                              hipStream_t stream) {
  const void* x  = d_in[0];
  const void* W1 = d_in[1];
  const void* b1 = d_in[2];
  const void* W2 = d_in[3];
  const void* b2 = d_in[4];
  const void* W3 = d_in[5];
  const void* b3 = d_in[6];

  const int NR = 8192, DIN = 1024, DH = 4096, DOUT = 1024;

  char* ws = (char*)d_ws;
  size_t off = 0;
  int* mode = (int*)(ws + off);                        off += 256;
  unsigned short* W1b = (unsigned short*)(ws + off);   off += (size_t)DH * DIN * 2;
  unsigned short* W2b = (unsigned short*)(ws + off);   off += (size_t)DH * DH * 2;
  unsigned short* W3b = (unsigned short*)(ws + off);   off += (size_t)DOUT * DH * 2;
  unsigned short* xb  = (unsigned short*)(ws + off);   off += (size_t)NR * DIN * 2;
  unsigned short* y1  = (unsigned short*)(ws + off);   off += (size_t)NR * DH * 2;
  unsigned short* y2  = (unsigned short*)(ws + off);   off += (size_t)NR * DH * 2;
  unsigned short* y3  = (unsigned short*)(ws + off);   off += (size_t)NR * DOUT * 2;
  float* part1 = (float*)(ws + off);                   off += (size_t)NR * 64 * 4;
  float* part2 = (float*)(ws + off);                   off += (size_t)NR * 64 * 4;
  float* part3 = (float*)(ws + off);                   off += (size_t)NR * 16 * 4;
  float* sc0  = (float*)(ws + off);                    off += (size_t)NR * 4;
  float* x0c  = (float*)(ws + off);                    off += (size_t)NR * 4;
  float* sc1  = (float*)(ws + off);                    off += (size_t)NR * 4;
  float* c01  = (float*)(ws + off);                    off += (size_t)NR * 4;
  float* sc2  = (float*)(ws + off);                    off += (size_t)NR * 4;
  float* c02  = (float*)(ws + off);                    off += (size_t)NR * 4;
  float* ss3  = (float*)(ws + off);                    off += (size_t)NR * 4;
  float* w1c0 = (float*)(ws + off);                    off += (size_t)DH * 4;
  float* w2c0 = (float*)(ws + off);                    off += (size_t)DH * 4;
  float* w3c0 = (float*)(ws + off);                    off += (size_t)DOUT * 4;
  float* b1f  = (float*)(ws + off);                    off += (size_t)DH * 4;
  float* b2f  = (float*)(ws + off);                    off += (size_t)DH * 4;
  float* b3f  = (float*)(ws + off);                    off += (size_t)DOUT * 4;

  k_init<<<16, 256, 0, stream>>>((const unsigned short*)x, mode, b1, b2, b3, b1f, b2f, b3f);

  k_cvtw<128><<<(DH * DIN / 8 + 255) / 256, 256, 0, stream>>>(W1, W1b, mode, DH * DIN / 8, w1c0);
  k_cvtw<512><<<(DH * DH  / 8 + 255) / 256, 256, 0, stream>>>(W2, W2b, mode, DH * DH / 8, w2c0);
  k_cvtw<512><<<(DOUT * DH / 8 + 255) / 256, 256, 0, stream>>>(W3, W3b, mode, DOUT * DH / 8, w3c0);

  k_prep<<<NR, 256, 0, stream>>>(x, xb, sc0, x0c, mode);

  k_g128<4096, 1024><<<1024, 256, 0, stream>>>(
      xb, W1b, b1f, sc0, x0c, w1c0, y1, part1);
  k_sc<64><<<(NR + 255) / 256, 256, 0, stream>>>(part1, y1, DH, sc1, c01, nullptr, NR);

  k_g128<4096, 4096><<<1024, 256, 0, stream>>>(
      y1, W2b, b2f, sc1, c01, w2c0, y2, part2);
  k_sc<64><<<(NR + 255) / 256, 256, 0, stream>>>(part2, y2, DH, sc2, c02, nullptr, NR);

  k_gemm_bt<1024, 4096, 16, 8><<<512, 256, 0, stream>>>(
      y2, W3b, b3f, sc2, c02, w3c0, y3, part3);
  k_sc<16><<<(NR + 255) / 256, 256, 0, stream>>>(part3, y3, DOUT, sc0, x0c, ss3, NR);

  k_final<<<NR, 256, 0, stream>>>(y3, ss3, d_out, mode);
}

// Round 8
// 598.244 us; speedup vs baseline: 1.0205x; 1.0205x over previous
//
#include <hip/hip_runtime.h>
#include <stdint.h>

#define EPSF 1e-7f
#define MAXTAN 10.0f

typedef __bf16 bf16x8 __attribute__((ext_vector_type(8)));
typedef float floatx4 __attribute__((ext_vector_type(4)));
typedef __attribute__((address_space(3))) void lds_void_t;
typedef __attribute__((address_space(1))) void gbl_void_t;

__device__ __forceinline__ unsigned short f2bf(float x) {
  union { float f; uint32_t u; } v; v.f = x;
  uint32_t u = v.u;
  u += 0x7fffu + ((u >> 16) & 1u);   // RNE
  return (unsigned short)(u >> 16);
}
__device__ __forceinline__ float bf2f(unsigned short h) {
  union { uint32_t u; float f; } v; v.u = ((uint32_t)h) << 16;
  return v.f;
}

__device__ __forceinline__ int sniff_mode(const unsigned short* x) {
  int sane = 0;
  for (int i = 0; i < 128; ++i) {
    unsigned short h = x[i];
    int e = (h >> 7) & 0xFF;
    if ((h & 0x7FFF) == 0 || (e >= 96 && e <= 140)) ++sane;
  }
  return (sane >= 120) ? 1 : 0;
}

// ---------------- init: sniff dtype + convert biases ----------------
__global__ void k_init(const unsigned short* __restrict__ x, int* __restrict__ modeg,
                       const void* __restrict__ b1, const void* __restrict__ b2,
                       const void* __restrict__ b3, float* __restrict__ o1,
                       float* __restrict__ o2, float* __restrict__ o3) {
  __shared__ int mds;
  if (threadIdx.x == 0) {
    int m = sniff_mode(x);
    mds = m;
    if (blockIdx.x == 0) *modeg = m;
  }
  __syncthreads();
  int m = mds;
  int i = blockIdx.x * 256 + threadIdx.x;
  if (i < 4096) o1[i] = m ? bf2f(((const unsigned short*)b1)[i]) : ((const float*)b1)[i];
  if (i < 4096) o2[i] = m ? bf2f(((const unsigned short*)b2)[i]) : ((const float*)b2)[i];
  if (i < 1024) o3[i] = m ? bf2f(((const unsigned short*)b3)[i]) : ((const float*)b3)[i];
}

// ---------------- x prep: convert to bf16, compute logmap scale + x0 ----------------
__global__ void k_prep(const void* __restrict__ xv, unsigned short* __restrict__ xb,
                       float* __restrict__ sc0, float* __restrict__ x0c,
                       const int* __restrict__ mode) {
  const int row = blockIdx.x;
  const int tid = threadIdx.x;
  float4 v;
  if (*mode) {
    ushort4 u = ((const ushort4*)((const unsigned short*)xv + (size_t)row * 1024))[tid];
    v.x = bf2f(u.x); v.y = bf2f(u.y); v.z = bf2f(u.z); v.w = bf2f(u.w);
  } else {
    v = ((const float4*)((const float*)xv + (size_t)row * 1024))[tid];
  }
  ushort4 o;
  o.x = f2bf(v.x); o.y = f2bf(v.y); o.z = f2bf(v.z); o.w = f2bf(v.w);
  ((ushort4*)(xb + (size_t)row * 1024))[tid] = o;

  float s = v.x * v.x + v.y * v.y + v.z * v.z + v.w * v.w;
  if (tid == 0) s -= v.x * v.x;          // exclude time coordinate
  for (int off = 32; off; off >>= 1) s += __shfl_down(s, off, 64);
  __shared__ float red[4];
  if ((tid & 63) == 0) red[tid >> 6] = s;
  __syncthreads();
  if (tid == 0) {
    s = red[0] + red[1] + red[2] + red[3];
    float ns = fmaxf(sqrtf(s), EPSF);
    float d = acoshf(fmaxf(v.x, 1.0f + EPSF));
    sc0[row] = d / ns;
    x0c[row] = bf2f(o.x);
  }
}

// ---------------- weight convert to bf16 + col0 extraction ----------------
template<int K8>
__global__ void k_cvtw(const void* __restrict__ in, unsigned short* __restrict__ out,
                       const int* __restrict__ mode, int n8, float* __restrict__ c0) {
  int i = blockIdx.x * 256 + threadIdx.x;
  if (i >= n8) return;
  if (*mode) {
    uint4 g = ((const uint4*)in)[i];
    ((uint4*)out)[i] = g;
    if (i % K8 == 0) c0[i / K8] = bf2f((unsigned short)(g.x & 0xFFFFu));
  } else {
    float4 a = ((const float4*)in)[2 * i];
    float4 b = ((const float4*)in)[2 * i + 1];
    ushort4 oa, ob;
    oa.x = f2bf(a.x); oa.y = f2bf(a.y); oa.z = f2bf(a.z); oa.w = f2bf(a.w);
    ob.x = f2bf(b.x); ob.y = f2bf(b.y); ob.z = f2bf(b.z); ob.w = f2bf(b.w);
    ((ushort4*)out)[2 * i] = oa;
    ((ushort4*)out)[2 * i + 1] = ob;
    if (i % K8 == 0) c0[i / K8] = bf2f(oa.x);
  }
}

// ---------------- partial-sumsq fold -> scale + col0 grab ----------------
template<int NBLK>
__global__ void k_sc(const float* __restrict__ part, const unsigned short* __restrict__ y,
                     int stride, float* __restrict__ sc, float* __restrict__ c0,
                     float* __restrict__ ssout, int nrows) {
  int i = blockIdx.x * 256 + threadIdx.x;
  if (i >= nrows) return;
  float s = 0.f;
#pragma unroll
  for (int j = 0; j < NBLK; ++j) s += part[(size_t)i * NBLK + j];
  float n = fmaxf(sqrtf(fmaxf(s, 0.f)), EPSF);
  sc[i] = fminf(n, MAXTAN) / n;
  c0[i] = bf2f(y[(size_t)i * stride]);
  if (ssout) ssout[i] = s;
}

// ---------------- final: y3 bf16 + ss3 -> projx(safe_expmap0(y3)) ----------------
__global__ void k_final(const unsigned short* __restrict__ y, const float* __restrict__ ss,
                        void* __restrict__ outv, const int* __restrict__ mode) {
  const int row = blockIdx.x;
  const int tid = threadIdx.x;
  float n = fmaxf(sqrtf(fmaxf(ss[row], 0.f)), EPSF);
  float nc = fminf(n, MAXTAN);
  float a = sinhf(nc) / n;
  ushort4 u = ((const ushort4*)(y + (size_t)row * 1024))[tid];
  float4 o;
  o.x = bf2f(u.x) * a; o.y = bf2f(u.y) * a;
  o.z = bf2f(u.z) * a; o.w = bf2f(u.w) * a;
  if (tid == 0) o.x = coshf(nc);
  if (*mode) {
    ushort4 o16;
    o16.x = f2bf(o.x); o16.y = f2bf(o.y); o16.z = f2bf(o.z); o16.w = f2bf(o.w);
    ((ushort4*)outv)[(size_t)row * 256 + tid] = o16;
  } else {
    ((float4*)outv)[(size_t)row * 256 + tid] = o;
  }
}

// ---------------- legacy 128x128 NT GEMM (kept for GEMM3) ----------------
template<int N, int K, int NBLK, int GX>
__global__ __launch_bounds__(256, 4) void k_gemm_bt(
    const unsigned short* __restrict__ A,
    const unsigned short* __restrict__ B,
    const float* __restrict__ bias,
    const float* __restrict__ sc,
    const float* __restrict__ c0f,
    const float* __restrict__ wc0,
    unsigned short* __restrict__ Cb,
    float* __restrict__ part)
{
  __shared__ __align__(16) unsigned short As[128 * 32];
  __shared__ __align__(16) unsigned short Bs[128 * 32];

  const int tid  = threadIdx.x;
  const int wave = tid >> 6;
  const int lane = tid & 63;
  const int quad = lane >> 4;
  const int m16  = lane & 15;

  const int j = blockIdx.x & 7;
  const int k = blockIdx.x >> 3;
  int bxi, byi;
  if (GX == 32) {
    bxi = 16 * (j & 1) + (k & 15);
    byi = 16 * (j >> 1) + (k >> 4);
  } else {
    bxi = k & 7;
    byi = 8 * j + (k >> 3);
  }
  const int bm = byi * 128;
  const int bn = bxi * 128;

  const int srow = lane >> 2;
  const int scol = (((lane & 3) ^ ((srow >> 1) & 3)) << 3);

  const int wm = (wave >> 1) << 6;
  const int wn = (wave & 1) << 6;

  const int rsw = ((quad ^ ((m16 >> 1) & 3)) << 3);

  const int c0i = wave * 2;
  const unsigned short* ga0 = A + (size_t)(bm + c0i * 16 + srow) * K + scol;
  const unsigned short* ga1 = ga0 + (size_t)16 * K;
  const unsigned short* gb0 = B + (size_t)(bn + c0i * 16 + srow) * K + scol;
  const unsigned short* gb1 = gb0 + (size_t)16 * K;

  floatx4 acc[4][4];
#pragma unroll
  for (int i = 0; i < 4; ++i)
#pragma unroll
    for (int jj = 0; jj < 4; ++jj)
#pragma unroll
      for (int r = 0; r < 4; ++r) acc[i][jj][r] = 0.0f;

  for (int k0 = 0; k0 < K; k0 += 32) {
    __builtin_amdgcn_global_load_lds((gbl_void_t*)(void*)ga0,
                                     (lds_void_t*)(As + c0i * 512), 16, 0, 0);
    __builtin_amdgcn_global_load_lds((gbl_void_t*)(void*)ga1,
                                     (lds_void_t*)(As + c0i * 512 + 512), 16, 0, 0);
    __builtin_amdgcn_global_load_lds((gbl_void_t*)(void*)gb0,
                                     (lds_void_t*)(Bs + c0i * 512), 16, 0, 0);
    __builtin_amdgcn_global_load_lds((gbl_void_t*)(void*)gb1,
                                     (lds_void_t*)(Bs + c0i * 512 + 512), 16, 0, 0);
    ga0 += 32; ga1 += 32; gb0 += 32; gb1 += 32;
    __syncthreads();

    bf16x8 af[4], bfg[4];
#pragma unroll
    for (int t = 0; t < 4; ++t) {
      af[t]  = *(const bf16x8*)(As + (wm + t * 16 + m16) * 32 + rsw);
      bfg[t] = *(const bf16x8*)(Bs + (wn + t * 16 + m16) * 32 + rsw);
    }
#pragma unroll
    for (int mt = 0; mt < 4; ++mt)
#pragma unroll
      for (int nt = 0; nt < 4; ++nt)
        acc[mt][nt] = __builtin_amdgcn_mfma_f32_16x16x32_bf16(af[mt], bfg[nt], acc[mt][nt], 0, 0, 0);
    __syncthreads();
  }

#pragma unroll
  for (int mt = 0; mt < 4; ++mt) {
#pragma unroll
    for (int r = 0; r < 4; ++r) {
      const int gm = bm + wm + mt * 16 + quad * 4 + r;
      const float scv = sc[gm];
      const float c0v = c0f[gm];
      float sq = 0.f;
#pragma unroll
      for (int nt = 0; nt < 4; ++nt) {
        const int gn = bn + wn + nt * 16 + m16;
        float v = scv * (acc[mt][nt][r] - c0v * wc0[gn]) + bias[gn];
        Cb[(size_t)gm * N + gn] = f2bf(v);
        sq += (gn == 0) ? 0.f : v * v;
      }
      sq += __shfl_xor(sq, 1, 64);
      sq += __shfl_xor(sq, 2, 64);
      sq += __shfl_xor(sq, 4, 64);
      sq += __shfl_xor(sq, 8, 64);
      if (m16 == 0) part[(size_t)gm * NBLK + 2 * bxi + (wave & 1)] = sq;
    }
  }
}

// ---------------- 256x256 NT GEMM, m201-style 8-phase schedule (R8) ----------------
// 512 thr = 8 waves (2M x 4N); per-wave 128x64 out (acc[8][4]); BK=64; 2-dbuf LDS 128KB.
// LDS byte layout: d*65536 + mat*32768 + half*16384 + row*128 + pg*16
//   (mat: A=0/B=1; half: A-> M-half (=wr), B-> N-half (=wc>>1); row within half; pg = 16B granule of 8)
// Granule swizzle (BK=64 re-derivation of the verified scheme): physical pg =
//   logical(ks*4+quad) ^ (row&7) -> 64 lanes spread 8/bank-group (balanced = floor);
//   GLL source pre-swizzled with the same involution: thread t: row=t>>3, pg=t&7,
//   src granule = (t&7)^((t>>3)&7).
// Iter = 2 K-tiles (E=2i dbuf0, O=2i+1 dbuf1), 8 phases, each:
//   [<=12 ds_read | 4 GLL at P1/P4/P5/P8] -> s_barrier -> setprio(1) 16 MFMA setprio(0)
//   -> [vmcnt(4) at P4/P8] -> s_barrier
// Quadrants per wave: (mh,nh) of its 128x64; phases P1..P4 = tile E quads (0,0),(0,1),(1,0),(1,1);
//   P5..P8 same for tile O. Reads: A(mh) 8x b128 at its first phase, B(nh) 4x b128 at its first.
// Staging stream (4 GLL each): P1: O.h1(A1+B1) | P4: E''.h0 | P5: E''.h1 | P8: O''.h0
//   (E''=2i+2 dbuf0, O''=2i+3 dbuf1; tail iters clamp source col -- rewrite same data, WAR-safe).
// vmcnt(4) ledger: end-P4: outstanding = P4's 4 -> P1's stage landed -> tile O fully
//   resident for P5 reads. end-P8: outstanding = P8's 4 -> P4+P5 landed -> E'' resident
//   for next-P1. WAR: dbuf0 written P4/P5 (last dbuf0 read = P3); dbuf1 written P8/P1
//   (last dbuf1 read = P7). Prologue: tile0 (8 GLL) + tile1.h0 (4 GLL); vmcnt(4); barrier.
// Epilogue identical to verified kernels: C/D col=lane&15, row=quad*4+r;
//   y = sc[m]*(acc - c0f[m]*wc0[n]) + bias[n]; partials part[gm*64 + bxi*4 + wc].
template<int N, int K>
__global__ __launch_bounds__(512, 2) void k_g8p(
    const unsigned short* __restrict__ A,
    const unsigned short* __restrict__ B,
    const float* __restrict__ bias,
    const float* __restrict__ sc,
    const float* __restrict__ c0f,
    const float* __restrict__ wc0,
    unsigned short* __restrict__ Cb,
    float* __restrict__ part)
{
  static_assert(K % 128 == 0, "need whole iters of 2x64-K tiles");
  constexpr int NTILES = K / 64;
  constexpr int NI = NTILES / 2;
  __shared__ __align__(16) unsigned short S[2][2][2][128][64];  // [dbuf][mat][half][row][col]

  const int tid  = threadIdx.x;
  const int wave = tid >> 6;
  const int lane = tid & 63;
  const int quad = lane >> 4;
  const int m16  = lane & 15;
  const int wr   = wave >> 2;     // 0..1 (M half)
  const int wc   = wave & 3;      // 0..3 (N column)

  // bijective XCD swizzle: 512 blocks = 8 XCDs x 64; each XCD an 8x8 patch
  const int j = blockIdx.x & 7;
  const int k = blockIdx.x >> 3;                 // 0..63
  const int bxi = 8 * (j & 1) + (k & 7);         // 0..15  (N/256)
  const int byi = 8 * (j >> 1) + (k >> 3);       // 0..31  (M/256)
  const int bm = byi * 256;
  const int bn = bxi * 256;

  // ---- staging pointers: thread t -> row t>>3 (0..63), pg t&7, src granule pre-swizzled
  const int srow = tid >> 3;
  const int sgr  = (tid & 7) ^ (srow & 7);
  const unsigned short* pA0g = A + (size_t)(bm + srow) * K + sgr * 8;          // A rows 0-63
  const unsigned short* pA1g = pA0g + (size_t)64 * K;                          // 64-127
  const unsigned short* pA2g = pA0g + (size_t)128 * K;                         // 128-191
  const unsigned short* pA3g = pA0g + (size_t)192 * K;                         // 192-255
  const unsigned short* pB0g = B + (size_t)(bn + srow) * K + sgr * 8;
  const unsigned short* pB1g = pB0g + (size_t)64 * K;
  const unsigned short* pB2g = pB0g + (size_t)128 * K;
  const unsigned short* pB3g = pB0g + (size_t)192 * K;
  char* dA = (char*)S + (size_t)(tid >> 3) * 128 + (tid & 7) * 16;   // + d*65536 + half*16384 + chunk*8192
  char* dB = dA + 32768;

  // ---- read-side lane bases: pg0 = (quad)^(m16&7) pattern, ks flips bit2 (^64 bytes)
  const int pg0 = (((m16 >> 2) & 1) << 2) | (quad ^ (m16 & 3));
  const int lb0 = m16 * 128 + pg0 * 16;
  const int lb1 = lb0 ^ 64;
  const char* Sb = (const char*)S;
  const char* pAk0d0 = Sb + wr * 16384 + lb0;            // A, ks=0, dbuf0
  const char* pAk1d0 = Sb + wr * 16384 + lb1;
  const char* pAk0d1 = pAk0d0 + 65536;
  const char* pAk1d1 = pAk1d0 + 65536;
  const char* pBk0d0 = Sb + 32768 + (wc >> 1) * 16384 + (wc & 1) * 8192 + lb0;
  const char* pBk1d0 = Sb + 32768 + (wc >> 1) * 16384 + (wc & 1) * 8192 + lb1;
  const char* pBk0d1 = pBk0d0 + 65536;
  const char* pBk1d1 = pBk1d0 + 65536;

  floatx4 acc[8][4];
#pragma unroll
  for (int i = 0; i < 8; ++i)
#pragma unroll
    for (int jj = 0; jj < 4; ++jj)
#pragma unroll
      for (int r = 0; r < 4; ++r) acc[i][jj][r] = 0.0f;

#define GLL(SRC, DST) __builtin_amdgcn_global_load_lds((gbl_void_t*)(void*)(SRC), (lds_void_t*)(DST), 16, 0, 0)
#define STGH0(D, COL) { GLL(pA0g + (COL), dA + (D) * 65536);         GLL(pA1g + (COL), dA + (D) * 65536 + 8192); \
                        GLL(pB0g + (COL), dB + (D) * 65536);         GLL(pB1g + (COL), dB + (D) * 65536 + 8192); }
#define STGH1(D, COL) { GLL(pA2g + (COL), dA + (D) * 65536 + 16384); GLL(pA3g + (COL), dA + (D) * 65536 + 24576); \
                        GLL(pB2g + (COL), dB + (D) * 65536 + 16384); GLL(pB3g + (COL), dB + (D) * 65536 + 24576); }
#define RDA(D, MH, DST) { _Pragma("unroll") for (int f = 0; f < 4; ++f) { \
    DST[f][0] = *(const bf16x8*)(((D) ? pAk0d1 : pAk0d0) + (MH) * 8192 + f * 2048); \
    DST[f][1] = *(const bf16x8*)(((D) ? pAk1d1 : pAk1d0) + (MH) * 8192 + f * 2048); } }
#define RDB(D, NH, DST) { _Pragma("unroll") for (int nt = 0; nt < 2; ++nt) { \
    DST[nt][0] = *(const bf16x8*)(((D) ? pBk0d1 : pBk0d0) + (NH) * 4096 + nt * 2048); \
    DST[nt][1] = *(const bf16x8*)(((D) ? pBk1d1 : pBk1d0) + (NH) * 4096 + nt * 2048); } }
#define MFMAQ(MH, NH, AARR, BARR) { \
    __builtin_amdgcn_s_setprio(1); \
    _Pragma("unroll") for (int f = 0; f < 4; ++f) \
      _Pragma("unroll") for (int nt = 0; nt < 2; ++nt) \
        _Pragma("unroll") for (int ks = 0; ks < 2; ++ks) \
          acc[(MH) * 4 + f][(NH) * 2 + nt] = __builtin_amdgcn_mfma_f32_16x16x32_bf16( \
              AARR[f][ks], BARR[nt][ks], acc[(MH) * 4 + f][(NH) * 2 + nt], 0, 0, 0); \
    __builtin_amdgcn_s_setprio(0); }
#define BAR __builtin_amdgcn_s_barrier()
#define VM4 asm volatile("s_waitcnt vmcnt(4)" ::: "memory")

  // prologue: tile0 full (dbuf0) + tile1 h0 (dbuf1); vmcnt(4) -> tile0 resident
  STGH0(0, 0) STGH1(0, 0) STGH0(1, 64)
  VM4;
  BAR;

  bf16x8 aq[4][2], b0[2][2], b1[2][2];

  for (int i = 0; i < NI; ++i) {
    const int colE = i * 128;
    const int colO = colE + 64;
    const int colE2 = (i < NI - 1) ? colE + 128 : colE;   // E''=2i+2, clamped (rewrite same data)
    const int colO2 = (i < NI - 1) ? colO + 128 : colO;   // O''=2i+3, clamped

    // P1: E quad (0,0); stage O.h1
    RDA(0, 0, aq) RDB(0, 0, b0)
    STGH1(1, colO)
    BAR; MFMAQ(0, 0, aq, b0) BAR;
    // P2: E quad (0,1)
    RDB(0, 1, b1)
    BAR; MFMAQ(0, 1, aq, b1) BAR;
    // P3: E quad (1,0)
    RDA(0, 1, aq)
    BAR; MFMAQ(1, 0, aq, b0) BAR;
    // P4: E quad (1,1); stage E''.h0; checkpoint
    STGH0(0, colE2)
    BAR; MFMAQ(1, 1, aq, b1)
    VM4; BAR;
    // P5: O quad (0,0); stage E''.h1
    RDA(1, 0, aq) RDB(1, 0, b0)
    STGH1(0, colE2)
    BAR; MFMAQ(0, 0, aq, b0) BAR;
    // P6: O quad (0,1)
    RDB(1, 1, b1)
    BAR; MFMAQ(0, 1, aq, b1) BAR;
    // P7: O quad (1,0)
    RDA(1, 1, aq)
    BAR; MFMAQ(1, 0, aq, b0) BAR;
    // P8: O quad (1,1); stage O''.h0; checkpoint
    STGH0(1, colO2)
    BAR; MFMAQ(1, 1, aq, b1)
    VM4; BAR;
  }

  // drain outstanding global_load_lds before waves retire
  asm volatile("s_waitcnt vmcnt(0)" ::: "memory");

#undef VM4
#undef BAR
#undef MFMAQ
#undef RDB
#undef RDA
#undef STGH1
#undef STGH0
#undef GLL

  // epilogue: C/D layout col = lane&15, row = quad*4 + r
  const int wm = wr * 128;
  const int wn = wc * 64;
#pragma unroll
  for (int mt = 0; mt < 8; ++mt) {
#pragma unroll
    for (int r = 0; r < 4; ++r) {
      const int gm = bm + wm + mt * 16 + quad * 4 + r;
      const float scv = sc[gm];
      const float c0v = c0f[gm];
      float sq = 0.f;
#pragma unroll
      for (int nt = 0; nt < 4; ++nt) {
        const int gn = bn + wn + nt * 16 + m16;
        float v = scv * (acc[mt][nt][r] - c0v * wc0[gn]) + bias[gn];
        Cb[(size_t)gm * N + gn] = f2bf(v);
        sq += (gn == 0) ? 0.f : v * v;
      }
      sq += __shfl_xor(sq, 1, 64);
      sq += __shfl_xor(sq, 2, 64);
      sq += __shfl_xor(sq, 4, 64);
      sq += __shfl_xor(sq, 8, 64);
      if (m16 == 0) part[(size_t)gm * 64 + bxi * 4 + wc] = sq;
    }
  }
}

extern "C" void kernel_launch(void* const* d_in, const int* in_sizes, int n_in,
                              void* d_out, int out_size, void* d_ws, size_t ws_size,
                              hipStream_t stream) {
  const void* x  = d_in[0];
  const void* W1 = d_in[1];
  const void* b1 = d_in[2];
  const void* W2 = d_in[3];
  const void* b2 = d_in[4];
  const void* W3 = d_in[5];
  const void* b3 = d_in[6];

  const int NR = 8192, DIN = 1024, DH = 4096, DOUT = 1024;

  char* ws = (char*)d_ws;
  size_t off = 0;
  int* mode = (int*)(ws + off);                        off += 256;
  unsigned short* W1b = (unsigned short*)(ws + off);   off += (size_t)DH * DIN * 2;
  unsigned short* W2b = (unsigned short*)(ws + off);   off += (size_t)DH * DH * 2;
  unsigned short* W3b = (unsigned short*)(ws + off);   off += (size_t)DOUT * DH * 2;
  unsigned short* xb  = (unsigned short*)(ws + off);   off += (size_t)NR * DIN * 2;
  unsigned short* y1  = (unsigned short*)(ws + off);   off += (size_t)NR * DH * 2;
  unsigned short* y2  = (unsigned short*)(ws + off);   off += (size_t)NR * DH * 2;
  unsigned short* y3  = (unsigned short*)(ws + off);   off += (size_t)NR * DOUT * 2;
  float* part1 = (float*)(ws + off);                   off += (size_t)NR * 64 * 4;
  float* part2 = (float*)(ws + off);                   off += (size_t)NR * 64 * 4;
  float* part3 = (float*)(ws + off);                   off += (size_t)NR * 16 * 4;
  float* sc0  = (float*)(ws + off);                    off += (size_t)NR * 4;
  float* x0c  = (float*)(ws + off);                    off += (size_t)NR * 4;
  float* sc1  = (float*)(ws + off);                    off += (size_t)NR * 4;
  float* c01  = (float*)(ws + off);                    off += (size_t)NR * 4;
  float* sc2  = (float*)(ws + off);                    off += (size_t)NR * 4;
  float* c02  = (float*)(ws + off);                    off += (size_t)NR * 4;
  float* ss3  = (float*)(ws + off);                    off += (size_t)NR * 4;
  float* w1c0 = (float*)(ws + off);                    off += (size_t)DH * 4;
  float* w2c0 = (float*)(ws + off);                    off += (size_t)DH * 4;
  float* w3c0 = (float*)(ws + off);                    off += (size_t)DOUT * 4;
  float* b1f  = (float*)(ws + off);                    off += (size_t)DH * 4;
  float* b2f  = (float*)(ws + off);                    off += (size_t)DH * 4;
  float* b3f  = (float*)(ws + off);                    off += (size_t)DOUT * 4;

  k_init<<<16, 256, 0, stream>>>((const unsigned short*)x, mode, b1, b2, b3, b1f, b2f, b3f);

  k_cvtw<128><<<(DH * DIN / 8 + 255) / 256, 256, 0, stream>>>(W1, W1b, mode, DH * DIN / 8, w1c0);
  k_cvtw<512><<<(DH * DH  / 8 + 255) / 256, 256, 0, stream>>>(W2, W2b, mode, DH * DH / 8, w2c0);
  k_cvtw<512><<<(DOUT * DH / 8 + 255) / 256, 256, 0, stream>>>(W3, W3b, mode, DOUT * DH / 8, w3c0);

  k_prep<<<NR, 256, 0, stream>>>(x, xb, sc0, x0c, mode);

  k_g8p<4096, 1024><<<512, 512, 0, stream>>>(
      xb, W1b, b1f, sc0, x0c, w1c0, y1, part1);
  k_sc<64><<<(NR + 255) / 256, 256, 0, stream>>>(part1, y1, DH, sc1, c01, nullptr, NR);

  k_g8p<4096, 4096><<<512, 512, 0, stream>>>(
      y1, W2b, b2f, sc1, c01, w2c0, y2, part2);
  k_sc<64><<<(NR + 255) / 256, 256, 0, stream>>>(part2, y2, DH, sc2, c02, nullptr, NR);

  k_gemm_bt<1024, 4096, 16, 8><<<512, 256, 0, stream>>>(
      y2, W3b, b3f, sc2, c02, w3c0, y3, part3);
  k_sc<16><<<(NR + 255) / 256, 256, 0, stream>>>(part3, y3, DOUT, sc0, x0c, ss3, NR);

  k_final<<<NR, 256, 0, stream>>>(y3, ss3, d_out, mode);
}